// Round 1
// baseline (191.415 us; speedup 1.0000x reference)
//
#include <hip/hip_runtime.h>

// GaussianVectorQuantizer: N=32768 rows (bs*W*H), D=64, K=512, T=0.5
// out[0..2097151] = z_to_decoder [32][64][32][32], out[2097152]=loss, out[2097153]=perplexity

#define NROW   32768
#define KDIC   512
#define DDIM   64
#define WGS    512
#define NWG    512          // 64 rows per WG (8 waves x 8 rows)

#define CT_LD  513          // +1 pad: conflict-free for both access patterns
#define ZQS_LD 72           // pad for transpose-store
#define SMEM_FLOATS (DDIM*CT_LD + 8*8*ZQS_LD + KDIC)
#define SMEM_BYTES  (SMEM_FLOATS*4)

__device__ __forceinline__ float rlane(float v, int l) {
  return __int_as_float(__builtin_amdgcn_readlane(__float_as_int(v), l));
}

__device__ __forceinline__ float half_prec(const float* var_q) {
  float vq = var_q[0];
  float pq = fminf(1.0f / fmaxf(vq, 1e-5f), 1e5f);
  return 0.5f * pq;
}

// ws layout (floats): [0] loss accumulator, [4..515] probs accumulator, [516..1027] hp*||c_k||^2
__global__ void k_pre(const float* __restrict__ var_q,
                      const float* __restrict__ cb,
                      float* __restrict__ ws) {
  int t = threadIdx.x;            // 512 threads
  float hp = half_prec(var_q);
  if (t == 0) ws[0] = 0.0f;
  ws[4 + t] = 0.0f;
  const float4* row = (const float4*)(cb + t * DDIM);
  float s = 0.0f;
  #pragma unroll
  for (int i = 0; i < 16; ++i) {
    float4 v = row[i];
    s += v.x*v.x + v.y*v.y + v.z*v.z + v.w*v.w;
  }
  ws[516 + t] = hp * s;
}

__global__ __launch_bounds__(WGS, 2) void k_main(
    const float* __restrict__ z, const float* __restrict__ var_q,
    const float* __restrict__ cb, const float* __restrict__ gu,
    float* __restrict__ out, float* __restrict__ ws)
{
  extern __shared__ float smem[];
  float* cT  = smem;                       // [64][513]  codebook^T
  float* zqs = smem + DDIM*CT_LD;          // [8 waves][8][72] staging for transpose-store
  float* pr  = zqs + 8*8*ZQS_LD;           // [512] per-WG probs reduction

  const int tid  = threadIdx.x;
  const int lane = tid & 63;
  const int wv   = tid >> 6;

  const float hp    = half_prec(var_q);
  const float twoHp = 2.0f * hp;

  pr[tid] = 0.0f;

  // stage transposed codebook (coalesced float4 loads)
  const float4* cb4 = (const float4*)cb;
  #pragma unroll
  for (int i = 0; i < 16; ++i) {
    int fi = tid + WGS * i;
    float4 v = cb4[fi];
    int k  = fi >> 4;
    int d0 = (fi & 15) << 2;
    cT[(d0+0)*CT_LD + k] = v.x;
    cT[(d0+1)*CT_LD + k] = v.y;
    cT[(d0+2)*CT_LD + k] = v.z;
    cT[(d0+3)*CT_LD + k] = v.w;
  }
  __syncthreads();

  const int row0 = blockIdx.x * 64 + wv * 8;   // 8 consecutive rows for this wave
  const int b    = row0 >> 10;                 // batch index (1024 rows per batch)
  const int wh   = row0 & 1023;

  // z: lane holds dim d=lane for rows r=0..7 (rows are consecutive wh -> float4 pairs)
  const float* zp = z + ((size_t)(b * DDIM + lane) << 10) + wh;
  float zr[8];
  {
    float4 a = *(const float4*)zp;
    float4 c = *(const float4*)(zp + 4);
    zr[0]=a.x; zr[1]=a.y; zr[2]=a.z; zr[3]=a.w;
    zr[4]=c.x; zr[5]=c.y; zr[6]=c.z; zr[7]=c.w;
  }

  // hp*||c_k||^2 for this lane's 8 codes
  float cnr[8];
  {
    const float4* cp = (const float4*)(ws + 516 + (lane << 3));
    float4 a = cp[0], c = cp[1];
    cnr[0]=a.x; cnr[1]=a.y; cnr[2]=a.z; cnr[3]=a.w;
    cnr[4]=c.x; cnr[5]=c.y; cnr[6]=c.z; cnr[7]=c.w;
  }

  // ---- pass 1: logits t[r][k] = 2hp*(z.c) - hp*||c||^2  (row-const -hp*||z||^2 cancels)
  float acc[8][8];
  #pragma unroll
  for (int r = 0; r < 8; ++r)
    #pragma unroll
    for (int j = 0; j < 8; ++j) acc[r][j] = 0.0f;

  #pragma unroll 2
  for (int d = 0; d < DDIM; ++d) {
    const float4* cp = (const float4*)&cT[d*CT_LD + (lane << 3)];
    float4 ca = cp[0], cbv = cp[1];
    float cv[8] = {ca.x, ca.y, ca.z, ca.w, cbv.x, cbv.y, cbv.z, cbv.w};
    float zb[8];
    #pragma unroll
    for (int r = 0; r < 8; ++r) zb[r] = rlane(zr[r], d);
    #pragma unroll
    for (int r = 0; r < 8; ++r)
      #pragma unroll
      for (int j = 0; j < 8; ++j)
        acc[r][j] = fmaf(zb[r], cv[j], acc[r][j]);
  }

  #pragma unroll
  for (int r = 0; r < 8; ++r)
    #pragma unroll
    for (int j = 0; j < 8; ++j)
      acc[r][j] = fmaf(acc[r][j], twoHp, -cnr[j]);

  // gumbel uniforms (issued after pass1 to cap register pressure)
  float uu[8][8];
  #pragma unroll
  for (int r = 0; r < 8; ++r) {
    const float4* up = (const float4*)(gu + ((size_t)(row0 + r) << 9) + (lane << 3));
    float4 a = up[0], c = up[1];
    uu[r][0]=a.x; uu[r][1]=a.y; uu[r][2]=a.z; uu[r][3]=a.w;
    uu[r][4]=c.x; uu[r][5]=c.y; uu[r][6]=c.z; uu[r][7]=c.w;
  }

  // ---- per-row softmax stats + gumbel-softmax encodings (in-register, K=512)
  float pacc[8] = {0,0,0,0,0,0,0,0};
  float kd = 0.0f;   // sum_k p*log p, lane-uniform

  #pragma unroll
  for (int r = 0; r < 8; ++r) {
    float m = acc[r][0];
    #pragma unroll
    for (int j = 1; j < 8; ++j) m = fmaxf(m, acc[r][j]);
    #pragma unroll
    for (int o = 32; o > 0; o >>= 1) m = fmaxf(m, __shfl_xor(m, o));

    float pt[8]; float s1 = 0.0f, pl = 0.0f;
    #pragma unroll
    for (int j = 0; j < 8; ++j) {
      float l = fmaxf(acc[r][j] - m, -50.0f);   // clip(-50,50); upper clip is no-op
      acc[r][j] = l;
      float p = __expf(l);
      pt[j] = p; s1 += p; pl = fmaf(p, l, pl);
    }
    #pragma unroll
    for (int o = 32; o > 0; o >>= 1) { s1 += __shfl_xor(s1, o); pl += __shfl_xor(pl, o); }
    float inv1 = 1.0f / s1;
    kd += fmaf(pl, inv1, -__logf(s1));          // sum p*(l - log s1)
    #pragma unroll
    for (int j = 0; j < 8; ++j) pacc[j] = fmaf(pt[j], inv1, pacc[j]);

    // encodings: softmax(2*(l + g)),  g = -log(-log(u+eps)+eps)
    #pragma unroll
    for (int j = 0; j < 8; ++j) {
      float gi = __logf(uu[r][j] + 1e-10f);
      float g  = -__logf(1e-10f - gi);
      acc[r][j] = 2.0f * (acc[r][j] + g);
    }
    float m2 = acc[r][0];
    #pragma unroll
    for (int j = 1; j < 8; ++j) m2 = fmaxf(m2, acc[r][j]);
    #pragma unroll
    for (int o = 32; o > 0; o >>= 1) m2 = fmaxf(m2, __shfl_xor(m2, o));
    float s2 = 0.0f;
    #pragma unroll
    for (int j = 0; j < 8; ++j) {
      float e = __expf(acc[r][j] - m2);
      acc[r][j] = e; s2 += e;
    }
    #pragma unroll
    for (int o = 32; o > 0; o >>= 1) s2 += __shfl_xor(s2, o);
    float inv2 = 1.0f / s2;
    #pragma unroll
    for (int j = 0; j < 8; ++j) acc[r][j] *= inv2;
  }

  // ---- pass 2: zq[r][d=lane] = sum_k e[r][k]*c[k][d]
  float zq[8] = {0,0,0,0,0,0,0,0};
  #pragma unroll 2
  for (int sl = 0; sl < 64; ++sl) {
    const float4* cp = (const float4*)&cT[lane*CT_LD + (sl << 3)];
    float4 ca = cp[0], cbv = cp[1];
    float cv[8] = {ca.x, ca.y, ca.z, ca.w, cbv.x, cbv.y, cbv.z, cbv.w};
    #pragma unroll
    for (int r = 0; r < 8; ++r)
      #pragma unroll
      for (int j = 0; j < 8; ++j)
        zq[r] = fmaf(rlane(acc[r][j], sl), cv[j], zq[r]);
  }

  // kld_continuous partial: hp * sum (z - zq)^2
  float kc = 0.0f;
  #pragma unroll
  for (int r = 0; r < 8; ++r) { float d2 = zr[r] - zq[r]; kc = fmaf(d2, d2, kc); }
  kc *= hp;
  #pragma unroll
  for (int o = 32; o > 0; o >>= 1) kc += __shfl_xor(kc, o);

  if (lane == 0) atomicAdd(&ws[0], kd + kc);

  // store z_to_decoder with transpose via LDS (coalesced 32B segments)
  float* zw = zqs + wv * (8 * ZQS_LD);
  #pragma unroll
  for (int r = 0; r < 8; ++r) zw[r * ZQS_LD + lane] = zq[r];
  int c8 = lane & 7, g8 = lane >> 3;
  #pragma unroll
  for (int i = 0; i < 8; ++i) {
    int dd = (i << 3) + g8;
    out[((size_t)(b * DDIM + dd) << 10) + wh + c8] = zw[c8 * ZQS_LD + dd];
  }

  // probs accumulation: register -> LDS atomics -> one global atomic per slot per WG
  #pragma unroll
  for (int j = 0; j < 8; ++j) atomicAdd(&pr[(lane << 3) + j], pacc[j]);
  __syncthreads();
  atomicAdd(&ws[4 + tid], pr[tid]);
}

__global__ void k_fin(const float* __restrict__ ws, float* __restrict__ out) {
  __shared__ float red[8];
  int t = threadIdx.x;  // 512
  float a = fmaxf(ws[4 + t] * (1.0f / 32768.0f), 1e-10f);
  float h = -a * __logf(a + 1e-10f);
  #pragma unroll
  for (int o = 32; o > 0; o >>= 1) h += __shfl_xor(h, o);
  if ((t & 63) == 0) red[t >> 6] = h;
  __syncthreads();
  if (t == 0) {
    float H = 0.0f;
    #pragma unroll
    for (int i = 0; i < 8; ++i) H += red[i];
    out[2097152] = ws[0] * (1.0f / 32.0f);   // (kld_discrete + kld_continuous)
    out[2097153] = __expf(H);                // perplexity
  }
}

extern "C" void kernel_launch(void* const* d_in, const int* in_sizes, int n_in,
                              void* d_out, int out_size, void* d_ws, size_t ws_size,
                              hipStream_t stream) {
  const float* z  = (const float*)d_in[0];
  const float* vq = (const float*)d_in[1];
  const float* cb = (const float*)d_in[2];
  const float* gu = (const float*)d_in[3];
  float* out = (float*)d_out;
  float* ws  = (float*)d_ws;

  // 151,808 B dynamic LDS (> 64 KiB default) — opt in every call (idempotent, capture-safe)
  hipFuncSetAttribute((const void*)k_main, hipFuncAttributeMaxDynamicSharedMemorySize, SMEM_BYTES);

  hipLaunchKernelGGL(k_pre,  dim3(1),   dim3(512), 0,          stream, vq, cb, ws);
  hipLaunchKernelGGL(k_main, dim3(NWG), dim3(WGS), SMEM_BYTES, stream, z, vq, cb, gu, out, ws);
  hipLaunchKernelGGL(k_fin,  dim3(1),   dim3(512), 0,          stream, ws, out);
}

// Round 2
// 130.878 us; speedup vs baseline: 1.4625x; 1.4625x over previous
//
#include <hip/hip_runtime.h>

// GaussianVectorQuantizer on MI355X: N=32768 rows, D=64, K=512, T=0.5
// out[0..2097151] = z_to_decoder [32][64][32][32], out[2097152]=loss, out[2097153]=perplexity
//
// Round 2: f16 MFMA for both GEMMs.
//   Wave handles 16 rows. Pass1: logits[16x512] = (2hp*z)[16x64] @ cb^T, bias -hp||c||^2 via C-init.
//   Code permutation: lane c (=lane&15) owns codes c*32+t (t=0..31) -> contiguous gumbel float4 loads.
//   Pass2: zq[16x64] = enc[16x512] @ cb, enc handed A-fragment-wise through a 1.25KB/wave LDS chunk.
// LDS: cbB1 fragments 64KB + cbB2 fragments 64KB + 8 waves x 2560B chunk/zq-staging + pr[512] = 150KB.

typedef _Float16 half8 __attribute__((ext_vector_type(8)));
typedef float f32x4 __attribute__((ext_vector_type(4)));

#define SMEM_BYTES 153600

__device__ __forceinline__ float half_prec(const float* var_q) {
  float vq = var_q[0];
  float pq = fminf(1.0f / fmaxf(vq, 1e-5f), 1e5f);
  return 0.5f * pq;
}

// ws layout (floats): [0] loss acc, [4..515] avg-prob acc, [516..1027] hp*||c_k||^2
__global__ void k_pre(const float* __restrict__ var_q,
                      const float* __restrict__ cb,
                      float* __restrict__ ws) {
  int t = threadIdx.x;            // 512 threads
  float hp = half_prec(var_q);
  if (t == 0) ws[0] = 0.0f;
  ws[4 + t] = 0.0f;
  const float4* row = (const float4*)(cb + t * 64);
  float s = 0.0f;
  #pragma unroll
  for (int i = 0; i < 16; ++i) {
    float4 v = row[i];
    s += v.x*v.x + v.y*v.y + v.z*v.z + v.w*v.w;
  }
  ws[516 + t] = hp * s;
}

__global__ __launch_bounds__(512, 2) void k_main(
    const float* __restrict__ z, const float* __restrict__ vq,
    const float* __restrict__ cb, const float* __restrict__ gu,
    float* __restrict__ out, float* __restrict__ ws)
{
  extern __shared__ char smem[];
  _Float16* lB1 = (_Float16*)smem;               // 65536 B: pass1 B fragments
  _Float16* lB2 = (_Float16*)(smem + 65536);     // 65536 B: pass2 B fragments
  char*  chunkAll = smem + 131072;               // 8 waves x 2560 B
  float* pr = (float*)(smem + 151552);           // 512 f32 prob accumulator

  const int tid  = threadIdx.x;
  const int lane = tid & 63;
  const int wv   = tid >> 6;
  const int c    = lane & 15;     // within-tile col / z-row slot
  const int g    = lane >> 4;     // k-group

  pr[tid] = 0.0f;

  // ---- stage codebook into MFMA-fragment order ----
  // cbB1[t*2+kk][l][j] = f16 cb[code=(l&15)*32+t][dim=32*kk+8*(l>>4)+j]
  #pragma unroll
  for (int i = 0; i < 8; ++i) {
    int F = tid + 512*i;
    int l = F & 63, grp = F >> 6;
    int t = grp >> 1, kk = grp & 1;
    int cc = l & 15, gg = l >> 4;
    const float* src = cb + (cc*32 + t)*64 + kk*32 + gg*8;
    float4 v0 = *(const float4*)src;
    float4 v1 = *(const float4*)(src + 4);
    half8 h = { (_Float16)v0.x, (_Float16)v0.y, (_Float16)v0.z, (_Float16)v0.w,
                (_Float16)v1.x, (_Float16)v1.y, (_Float16)v1.z, (_Float16)v1.w };
    ((half8*)lB1)[F] = h;
  }
  // cbB2[kt*4+nt][l][j] = f16 cb[code=((kap&15)<<5)+2*kt+(kap>>4)][dim=nt*16+(l&15)], kap=8*(l>>4)+j
  #pragma unroll
  for (int i = 0; i < 8; ++i) {
    int F = tid + 512*i;
    int l = F & 63, grp = F >> 6;
    int kt = grp >> 2, nt = grp & 3;
    int cc = l & 15, gg = l >> 4;
    int dim = nt*16 + cc;
    half8 h;
    #pragma unroll
    for (int j = 0; j < 8; ++j) {
      int kap = gg*8 + j;
      int code = ((kap & 15) << 5) + 2*kt + (kap >> 4);
      h[j] = (_Float16)cb[code*64 + dim];
    }
    ((half8*)lB2)[F] = h;
  }
  __syncthreads();

  const float hp   = half_prec(vq);
  const float s2hp = 2.0f * hp;

  const int row0 = (blockIdx.x * 8 + wv) * 16;   // 16 rows per wave
  const int b    = row0 >> 10;
  const int wh0  = row0 & 1023;

  // ---- acc init: -hp*||c_k||^2, code = c*32+t ----
  f32x4 acc[32];
  {
    const float4* hn = (const float4*)(ws + 516 + c*32);
    #pragma unroll
    for (int u = 0; u < 8; ++u) {
      float4 h4 = hn[u];
      acc[4*u+0] = (f32x4){-h4.x, -h4.x, -h4.x, -h4.x};
      acc[4*u+1] = (f32x4){-h4.y, -h4.y, -h4.y, -h4.y};
      acc[4*u+2] = (f32x4){-h4.z, -h4.z, -h4.z, -h4.z};
      acc[4*u+3] = (f32x4){-h4.w, -h4.w, -h4.w, -h4.w};
    }
  }

  // ---- z A-fragments: row = row0+c, k-dims = 32*kk + 8*g + j, scaled by 2hp ----
  half8 zA0, zA1;
  {
    const float* zb = z + (size_t)(b*64)*1024 + wh0 + c;
    #pragma unroll
    for (int j = 0; j < 8; ++j) {
      zA0[j] = (_Float16)(zb[(size_t)(     g*8 + j)*1024] * s2hp);
      zA1[j] = (_Float16)(zb[(size_t)(32 + g*8 + j)*1024] * s2hp);
    }
  }

  // ---- pass 1: 64 MFMA -> acc[t][q] = logit[row0+4g+q][code c*32+t] ----
  const half8* B1 = (const half8*)lB1;
  #pragma unroll
  for (int t = 0; t < 32; ++t) {
    acc[t] = __builtin_amdgcn_mfma_f32_16x16x32_f16(zA0, B1[(t*2+0)*64 + lane], acc[t], 0, 0, 0);
    acc[t] = __builtin_amdgcn_mfma_f32_16x16x32_f16(zA1, B1[(t*2+1)*64 + lane], acc[t], 0, 0, 0);
  }

  // ---- softmax stats (rows 4g+q; reduce across the 16 lanes of group g) ----
  float mq[4];
  #pragma unroll
  for (int q = 0; q < 4; ++q) {
    float m = acc[0][q];
    #pragma unroll
    for (int t = 1; t < 32; ++t) m = fmaxf(m, acc[t][q]);
    #pragma unroll
    for (int o = 8; o > 0; o >>= 1) m = fmaxf(m, __shfl_xor(m, o));
    mq[q] = m;
  }
  #pragma unroll
  for (int t = 0; t < 32; ++t)
    #pragma unroll
    for (int q = 0; q < 4; ++q) acc[t][q] -= mq[q];

  float s1[4] = {0,0,0,0}, pl[4] = {0,0,0,0};
  #pragma unroll
  for (int t = 0; t < 32; ++t)
    #pragma unroll
    for (int q = 0; q < 4; ++q) {
      float p = __expf(acc[t][q]);
      s1[q] += p;
      pl[q] = fmaf(p, acc[t][q], pl[q]);
    }
  float kd = 0.0f, inv1[4];
  #pragma unroll
  for (int q = 0; q < 4; ++q) {
    #pragma unroll
    for (int o = 8; o > 0; o >>= 1) { s1[q] += __shfl_xor(s1[q], o); pl[q] += __shfl_xor(pl[q], o); }
    inv1[q] = 1.0f / s1[q];
    kd += pl[q] * inv1[q] - __logf(s1[q]);
  }

  // ---- avg-prob accumulation (codes c*32+t), pr layout [t][c] (conflict-free) ----
  #pragma unroll
  for (int t = 0; t < 32; ++t) {
    float v = 0.0f;
    #pragma unroll
    for (int q = 0; q < 4; ++q) v = fmaf(__expf(acc[t][q]), inv1[q], v);
    v += __shfl_xor(v, 16);
    v += __shfl_xor(v, 32);
    if (g == 0) atomicAdd(&pr[t*16 + c], v);
  }

  // ---- gumbel-softmax logits: acc <- 2*(l + g), g = -log(-log(u+eps)+eps) ----
  #pragma unroll
  for (int q = 0; q < 4; ++q) {
    const float4* ub = (const float4*)(gu + (size_t)(row0 + 4*g + q)*512 + c*32);
    #pragma unroll
    for (int tt = 0; tt < 8; ++tt) {
      float4 u4 = ub[tt];
      float y0 = 1e-10f - __logf(u4.x + 1e-10f);
      float y1 = 1e-10f - __logf(u4.y + 1e-10f);
      float y2 = 1e-10f - __logf(u4.z + 1e-10f);
      float y3 = 1e-10f - __logf(u4.w + 1e-10f);
      acc[4*tt+0][q] = 2.0f * (acc[4*tt+0][q] - __logf(y0));
      acc[4*tt+1][q] = 2.0f * (acc[4*tt+1][q] - __logf(y1));
      acc[4*tt+2][q] = 2.0f * (acc[4*tt+2][q] - __logf(y2));
      acc[4*tt+3][q] = 2.0f * (acc[4*tt+3][q] - __logf(y3));
    }
  }

  // ---- encoding softmax (in-place) ----
  #pragma unroll
  for (int q = 0; q < 4; ++q) {
    float m = acc[0][q];
    #pragma unroll
    for (int t = 1; t < 32; ++t) m = fmaxf(m, acc[t][q]);
    #pragma unroll
    for (int o = 8; o > 0; o >>= 1) m = fmaxf(m, __shfl_xor(m, o));
    float s = 0.0f;
    #pragma unroll
    for (int t = 0; t < 32; ++t) { float e = __expf(acc[t][q] - m); acc[t][q] = e; s += e; }
    #pragma unroll
    for (int o = 8; o > 0; o >>= 1) s += __shfl_xor(s, o);
    float inv = 1.0f / s;
    #pragma unroll
    for (int t = 0; t < 32; ++t) acc[t][q] *= inv;
  }

  // ---- pass 2: zq[16x64] = enc @ cb, chunked through per-wave LDS (double-buffered) ----
  f32x4 zacc[4];
  #pragma unroll
  for (int nt = 0; nt < 4; ++nt) zacc[nt] = (f32x4){0.f, 0.f, 0.f, 0.f};

  _Float16* myChunk = (_Float16*)(chunkAll + wv * 2560);
  const half8* B2 = (const half8*)lB2;
  #pragma unroll
  for (int kt = 0; kt < 16; ++kt) {
    _Float16* eS = myChunk + (kt & 1) * 640;     // [16 rows][40 halfs]
    #pragma unroll
    for (int tb = 0; tb < 2; ++tb)
      #pragma unroll
      for (int q = 0; q < 4; ++q)
        eS[(4*g + q)*40 + 16*tb + c] = (_Float16)acc[2*kt + tb][q];
    half8 ea = *(const half8*)(eS + c*40 + g*8); // A-frag: row=c, k=8g+j
    #pragma unroll
    for (int nt = 0; nt < 4; ++nt)
      zacc[nt] = __builtin_amdgcn_mfma_f32_16x16x32_f16(ea, B2[(kt*4 + nt)*64 + lane], zacc[nt], 0, 0, 0);
  }

  // ---- stage zq (f16), transpose to lane=dim, store + continuous KLD ----
  _Float16* zS = myChunk;                        // [16 rows][72 halfs], reuses chunk space
  #pragma unroll
  for (int nt = 0; nt < 4; ++nt)
    #pragma unroll
    for (int q = 0; q < 4; ++q)
      zS[(4*g + q)*72 + nt*16 + c] = (_Float16)zacc[nt][q];

  float kc = 0.0f;
  {
    const float* zr = z  + (size_t)(b*64 + lane)*1024 + wh0;
    float* orow     = out + (size_t)(b*64 + lane)*1024 + wh0;
    #pragma unroll
    for (int s = 0; s < 4; ++s) {
      float4 zv = *(const float4*)(zr + 4*s);
      float4 ov;
      ov.x = (float)zS[(4*s + 0)*72 + lane];
      ov.y = (float)zS[(4*s + 1)*72 + lane];
      ov.z = (float)zS[(4*s + 2)*72 + lane];
      ov.w = (float)zS[(4*s + 3)*72 + lane];
      float d0 = zv.x - ov.x, d1 = zv.y - ov.y, d2 = zv.z - ov.z, d3 = zv.w - ov.w;
      kc = fmaf(d0, d0, kc); kc = fmaf(d1, d1, kc);
      kc = fmaf(d2, d2, kc); kc = fmaf(d3, d3, kc);
      *(float4*)(orow + 4*s) = ov;
    }
  }
  kc *= hp;

  // ---- loss partial: kd duplicated over 16 c-lanes (/16), kc unique per lane ----
  float lv = kd * 0.0625f + kc;
  #pragma unroll
  for (int o = 32; o > 0; o >>= 1) lv += __shfl_xor(lv, o);
  if (lane == 0) atomicAdd(&ws[0], lv);

  __syncthreads();
  // pr[t*16+c] -> code c*32+t
  atomicAdd(ws + 4 + ((tid & 15)*32 + (tid >> 4)), pr[tid]);
}

__global__ void k_fin(const float* __restrict__ ws, float* __restrict__ out) {
  __shared__ float red[8];
  int t = threadIdx.x;  // 512
  float a = fmaxf(ws[4 + t] * (1.0f / 32768.0f), 1e-10f);
  float h = -a * __logf(a + 1e-10f);
  #pragma unroll
  for (int o = 32; o > 0; o >>= 1) h += __shfl_xor(h, o);
  if ((t & 63) == 0) red[t >> 6] = h;
  __syncthreads();
  if (t == 0) {
    float H = 0.0f;
    #pragma unroll
    for (int i = 0; i < 8; ++i) H += red[i];
    out[2097152] = ws[0] * (1.0f / 32.0f);
    out[2097153] = __expf(H);
  }
}

extern "C" void kernel_launch(void* const* d_in, const int* in_sizes, int n_in,
                              void* d_out, int out_size, void* d_ws, size_t ws_size,
                              hipStream_t stream) {
  const float* z  = (const float*)d_in[0];
  const float* vq = (const float*)d_in[1];
  const float* cb = (const float*)d_in[2];
  const float* gu = (const float*)d_in[3];
  float* out = (float*)d_out;
  float* ws  = (float*)d_ws;

  hipFuncSetAttribute((const void*)k_main, hipFuncAttributeMaxDynamicSharedMemorySize, SMEM_BYTES);

  hipLaunchKernelGGL(k_pre,  dim3(1),   dim3(512), 0,          stream, vq, cb, ws);
  hipLaunchKernelGGL(k_main, dim3(256), dim3(512), SMEM_BYTES, stream, z, vq, cb, gu, out, ws);
  hipLaunchKernelGGL(k_fin,  dim3(1),   dim3(512), 0,          stream, ws, out);
}